// Round 16
// baseline (117.463 us; speedup 1.0000x reference)
//
#include <hip/hip_runtime.h>
#include <hip/hip_fp16.h>

#define N_TOK 3136
#define DH 64
#define NHEAD 2
#define CDIM 128
#define BATCH 8
#define NT 49                      // kv tiles of 64
#define NUNITS (BATCH * NHEAD * 25) // 400 attn work units
#define MTILES ((BATCH * N_TOK) / 64) // 392
#define EXPBLKS (NHEAD * NT * (N_TOK / 64)) // 4802
#define QK_SCALE 0.18033688011112f // 0.125 * log2(e)
#define LOG2E 1.4426950408889634f

typedef __attribute__((ext_vector_type(8))) short bf16x8;
typedef __attribute__((ext_vector_type(8))) _Float16 f16x8;
typedef __attribute__((ext_vector_type(2))) _Float16 f16x2;
typedef __attribute__((ext_vector_type(2))) __fp16 fp16x2;
typedef __attribute__((ext_vector_type(4))) float f32x4;
typedef __attribute__((ext_vector_type(16))) float f32x16;
typedef __attribute__((ext_vector_type(4))) unsigned short u16x4;
typedef __attribute__((ext_vector_type(4))) unsigned int u32x4;

__device__ __forceinline__ unsigned short f2bf(float f) {
  unsigned int u = __float_as_uint(f);
  u += 0x7fffu + ((u >> 16) & 1u);
  return (unsigned short)(u >> 16);
}

#define MFMA16(a, b, c)    __builtin_amdgcn_mfma_f32_16x16x32_bf16(a, b, c, 0, 0, 0)
#define MFMA32_BF(a, b, c) __builtin_amdgcn_mfma_f32_32x32x16_bf16(a, b, c, 0, 0, 0)
#define MFMA32_F16(a, b, c) __builtin_amdgcn_mfma_f32_32x32x16_f16(a, b, c, 0, 0, 0)

__device__ __forceinline__ void plswap(unsigned& a, unsigned& b) {
  asm volatile("v_permlane32_swap_b32 %0, %1" : "+v"(a), "+v"(b));
}

__device__ __forceinline__ f16x2 pkrtz(float a, float b) {
  union { fp16x2 p; f16x2 h; } cv;
  cv.p = __builtin_amdgcn_cvt_pkrtz(a, b);
  return cv.h;
}

__device__ __forceinline__ float dot2acc(f16x2 pr, float acc) {
#if __has_builtin(__builtin_amdgcn_fdot2)
  union { f16x2 h; fp16x2 p; } c; c.h = pr;
  fp16x2 ones = {(__fp16)1.0f, (__fp16)1.0f};
  return __builtin_amdgcn_fdot2(c.p, ones, acc, false);
#else
  return acc + (float)pr[0] + (float)pr[1];
#endif
}

// ---------------------------------------------------------------------------
// Shared GEMM helpers (64-row x-tile  x  128x128 W, MFMA 16x16x32)
// ---------------------------------------------------------------------------
__device__ __forceinline__ void stage_w(const float* __restrict__ W,
                                        unsigned short (*wsh)[136], int tid) {
  const float4* Wv4 = (const float4*)W;
#pragma unroll
  for (int i = 0; i < 16; ++i) {
    int f = tid + i * 256;
    float4 v = Wv4[f];
    int row = f >> 5, col = (f & 31) << 2;
    u16x4 pk = { f2bf(v.x), f2bf(v.y), f2bf(v.z), f2bf(v.w) };
    *(u16x4*)&wsh[row][col] = pk;
  }
}

__device__ __forceinline__ void mfma_block(const unsigned short (*xs)[136],
                                           const unsigned short (*wsh)[136],
                                           int w, int lk, int lg, f32x4* acc) {
#pragma unroll
  for (int nf = 0; nf < 8; ++nf) acc[nf] = (f32x4){0.f, 0.f, 0.f, 0.f};
#pragma unroll
  for (int kk = 0; kk < 4; ++kk) {
    bf16x8 a = *(const bf16x8*)&xs[w * 16 + lk][kk * 32 + 8 * lg];
#pragma unroll
    for (int nf = 0; nf < 8; ++nf) {
      bf16x8 b = *(const bf16x8*)&wsh[nf * 16 + lk][kk * 32 + 8 * lg];
      acc[nf] = MFMA16(a, b, acc[nf]);
    }
  }
}

// ---------------------------------------------------------------------------
// pre_kernel: fused {QKV projection | exp(relpos)} — one grid so the BW-bound
// exp blocks overlap the MFMA-bound projection blocks.
// Q,K -> bf16 [b][h][tok][64] (Q pre-scaled); V -> f16 TRANSPOSED [b][h][d][tok].
// E[h][kt][q][didx] f16 = exp(relpos), didx = attn-fragment-ordered key.
// (Verbatim from R13/R15 — passed post-timing checks.)
// ---------------------------------------------------------------------------
__global__ __launch_bounds__(256)
void pre_kernel(const float* __restrict__ x,
                const float* __restrict__ Wq, const float* __restrict__ bq,
                const float* __restrict__ Wk, const float* __restrict__ bk,
                const float* __restrict__ Wv, const float* __restrict__ bv,
                unsigned short* __restrict__ qo, unsigned short* __restrict__ ko,
                unsigned short* __restrict__ vo,
                const float* __restrict__ rp, __half* __restrict__ E)
{
  __shared__ __align__(16) unsigned short xs[64][136];
  __shared__ __align__(16) unsigned short wsh[128][136];
  const int tid = threadIdx.x;

  if (blockIdx.x >= MTILES) {
    const int eb = blockIdx.x - MTILES;
    const int hkt = eb % (NHEAD * NT);
    const int q0 = (eb / (NHEAD * NT)) * 64;
    const int h = hkt / NT, kt = hkt % NT;
    const int kp = tid & 63;
    const int qi = tid >> 6;

    const int ct = kp >> 5;
    const int kpp = kp & 31;
    const int hi = (kpp >> 2) & 1;
    const int r = (kpp & 3) + ((kpp >> 3) << 2);
    const int didx = hi * 32 + ct * 16 + r;

    const float* src = rp + ((size_t)h * N_TOK + q0) * N_TOK + kt * 64 + kp;
    __half* dst = E + (((size_t)h * NT + kt) * N_TOK + q0) * 64 + didx;
#pragma unroll
    for (int i = 0; i < 16; ++i) {
      int q = qi * 16 + i;
      float v = __expf(src[(size_t)q * N_TOK]);
      dst[(size_t)q * 64] = __float2half(v);
    }
    return;
  }

  const int m0 = blockIdx.x * 64;
  const int w = tid >> 6, l = tid & 63;
  const int lk = l & 15, lg = l >> 4;

  {
    const float4* Xv = (const float4*)(x + (size_t)m0 * CDIM);
#pragma unroll
    for (int i = 0; i < 8; ++i) {
      int f = tid + i * 256;
      float4 v = Xv[f];
      int row = f >> 5, col = (f & 31) << 2;
      u16x4 pk = { f2bf(v.x), f2bf(v.y), f2bf(v.z), f2bf(v.w) };
      *(u16x4*)&xs[row][col] = pk;
    }
  }
  stage_w(Wq, wsh, tid);
  __syncthreads();

  f32x4 acc[8];

  // Q
  mfma_block(xs, wsh, w, lk, lg, acc);
#pragma unroll
  for (int reg = 0; reg < 4; ++reg) {
    int row = m0 + w * 16 + 4 * lg + reg;
    int bb = row / N_TOK, tok = row - bb * N_TOK;
#pragma unroll
    for (int nf = 0; nf < 8; ++nf) {
      int col = nf * 16 + lk;
      float val = (acc[nf][reg] + bq[col]) * QK_SCALE;
      qo[((size_t)(bb * NHEAD + (nf >> 2)) * N_TOK + tok) * DH + (col & 63)] = f2bf(val);
    }
  }
  __syncthreads();

  // K
  stage_w(Wk, wsh, tid);
  __syncthreads();
  mfma_block(xs, wsh, w, lk, lg, acc);
#pragma unroll
  for (int reg = 0; reg < 4; ++reg) {
    int row = m0 + w * 16 + 4 * lg + reg;
    int bb = row / N_TOK, tok = row - bb * N_TOK;
#pragma unroll
    for (int nf = 0; nf < 8; ++nf) {
      int col = nf * 16 + lk;
      float val = acc[nf][reg] + bk[col];
      ko[((size_t)(bb * NHEAD + (nf >> 2)) * N_TOK + tok) * DH + (col & 63)] = f2bf(val);
    }
  }
  __syncthreads();

  // V (transposed f16: [b][h][d][tok])
  stage_w(Wv, wsh, tid);
  __syncthreads();
  mfma_block(xs, wsh, w, lk, lg, acc);
#pragma unroll
  for (int reg = 0; reg < 4; ++reg) {
    int row = m0 + w * 16 + 4 * lg + reg;
    int bb = row / N_TOK, tok = row - bb * N_TOK;
#pragma unroll
    for (int nf = 0; nf < 8; ++nf) {
      int col = nf * 16 + lk;
      float val = acc[nf][reg] + bv[col];
      size_t idx = ((size_t)(bb * NHEAD + (nf >> 2)) * DH + (col & 63)) * N_TOK + tok;
      vo[idx] = __half_as_ushort(__float2half(val));
    }
  }
}

// ---------------------------------------------------------------------------
// attn32p: PERSISTENT work-stealing version of the R15-proven attention.
// 512 blocks (2/CU); each pulls (bh,qt) units off a global counter until the
// 400 units drain — removes the 78% integer-packing imbalance of the static
// 400-block grid. Per-unit body identical to R15 (output writes disjoint per
// unit => deterministic regardless of assignment order).
// ---------------------------------------------------------------------------
__global__ __launch_bounds__(256)
void attn32p(const unsigned short* __restrict__ q_ws,
             const unsigned short* __restrict__ k_ws,
             const unsigned short* __restrict__ v_ws,   // V^T [b][h][d][tok] f16
             const __half* __restrict__ E,
             unsigned short* __restrict__ attn_out,
             int* __restrict__ counter)
{
  __shared__ __align__(16) unsigned short LDSU[2][9216]; // [buf][K 4608 | V 4608]
  __shared__ int s_unit;

  const int tid = threadIdx.x;
  const int w = tid >> 6, l = tid & 63;
  const int lq = l & 31, hi = l >> 5;

  // unit-independent staging mapping: row = tid>>3 (+32), unit = tid&7
  const int kr0 = tid >> 3, ku = tid & 7;
  const int kofs = kr0 * 72 + ku * 8;
  const int gk0 = kr0 * DH + ku * 8, gk1 = gk0 + 32 * DH;
  const int gvt0 = kr0 * N_TOK + ku * 8, gvt1 = gvt0 + 32 * N_TOK;

  for (;;) {
    __syncthreads();                       // LDS safe to reuse; all waves here
    if (tid == 0) s_unit = atomicAdd(counter, 1);
    __syncthreads();
    const int u = s_unit;
    if (u >= NUNITS) return;

    const int bhid = u / 25, qt = u - bhid * 25;
    const int b = bhid >> 1, head = bhid & 1;

    const size_t bh = (size_t)bhid * N_TOK;
    const unsigned short* Kp = k_ws + bh * DH;
    const _Float16* Vt = (const _Float16*)v_ws + bh * DH;

    int qg = qt * 128 + w * 32 + lq;
    if (qg > N_TOK - 1) qg = N_TOK - 1;

    bf16x8 qf[4];
    {
      const unsigned short* qrow = q_ws + (bh + (size_t)qg) * DH + 8 * hi;
#pragma unroll
      for (int ks = 0; ks < 4; ++ks) qf[ks] = *(const bf16x8*)(qrow + 16 * ks);
    }

    const __half* Eb = E + (((size_t)head * NT) * N_TOK + (size_t)qg) * DH + hi * 32;

    float lsum0 = 0.f, lsum1 = 0.f;
    f32x16 o0, o1;
#pragma unroll
    for (int i = 0; i < 16; ++i) { o0[i] = 0.f; o1[i] = 0.f; }

    // ---- prologue: tile 0 ----
    bf16x8 kpreA = *(const bf16x8*)(Kp + gk0);
    bf16x8 kpreB = *(const bf16x8*)(Kp + gk1);
    f16x8 vpreA = *(const f16x8*)(Vt + gvt0);
    f16x8 vpreB = *(const f16x8*)(Vt + gvt1);

    u32x4 EwA[4], EwB[4];
    {
      const u32x4* ep = (const u32x4*)Eb;   // kt = 0
#pragma unroll
      for (int f = 0; f < 4; ++f) EwA[f] = ep[f];
    }

    *(bf16x8*)&LDSU[0][kofs] = kpreA;
    *(bf16x8*)&LDSU[0][kofs + 32 * 72] = kpreB;
    *(f16x8*)&LDSU[0][4608 + kofs] = vpreA;
    *(f16x8*)&LDSU[0][4608 + kofs + 32 * 72] = vpreB;
    {
      const unsigned short* kn = Kp + (size_t)64 * DH;
      const _Float16* vn = Vt + 64;
      kpreA = *(const bf16x8*)(kn + gk0);
      kpreB = *(const bf16x8*)(kn + gk1);
      vpreA = *(const f16x8*)(vn + gvt0);
      vpreB = *(const f16x8*)(vn + gvt1);
    }
    asm volatile("s_waitcnt lgkmcnt(0)" ::: "memory");
    __builtin_amdgcn_s_barrier();
    asm volatile("" ::: "memory");

#define ATTN_BODY(PH, KT, EW_CUR, EW_NXT, LAST)                               \
  {                                                                           \
    const unsigned short* Kb = &LDSU[PH][0];                                  \
    const unsigned short* Vb = &LDSU[PH][4608];                               \
    unsigned short* Kn = &LDSU[PH ^ 1][0];                                    \
    unsigned short* Vn = &LDSU[PH ^ 1][4608];                                 \
    if (!(LAST)) { /* issue E(kt+1) */                                        \
      const u32x4* ep = (const u32x4*)(Eb + (size_t)((KT) + 1) * (N_TOK * DH)); \
      _Pragma("unroll") for (int f = 0; f < 4; ++f) EW_NXT[f] = ep[f];        \
    }                                                                         \
    /* S^T = K * Q^T */                                                       \
    f32x16 s0, s1;                                                            \
    _Pragma("unroll") for (int i = 0; i < 16; ++i) { s0[i] = 0.f; s1[i] = 0.f; } \
    __builtin_amdgcn_s_setprio(1);                                            \
    _Pragma("unroll") for (int ks = 0; ks < 4; ++ks) {                        \
      bf16x8 kf0 = *(const bf16x8*)&Kb[lq * 72 + 16 * ks + 8 * hi];           \
      s0 = MFMA32_BF(kf0, qf[ks], s0);                                        \
      bf16x8 kf1 = *(const bf16x8*)&Kb[(32 + lq) * 72 + 16 * ks + 8 * hi];    \
      s1 = MFMA32_BF(kf1, qf[ks], s1);                                        \
    }                                                                         \
    __builtin_amdgcn_s_setprio(0);                                            \
    if (!(LAST)) { /* store tile kt+1 into other buf; issue kt+2 */           \
      *(bf16x8*)&Kn[kofs] = kpreA;                                            \
      *(bf16x8*)&Kn[kofs + 32 * 72] = kpreB;                                  \
      *(f16x8*)&Vn[kofs] = vpreA;                                             \
      *(f16x8*)&Vn[kofs + 32 * 72] = vpreB;                                   \
      if ((KT) + 2 < NT) {                                                    \
        const unsigned short* kn2 = Kp + (size_t)((KT) + 2) * 64 * DH;        \
        const _Float16* vn2 = Vt + (size_t)((KT) + 2) * 64;                   \
        kpreA = *(const bf16x8*)(kn2 + gk0);                                  \
        kpreB = *(const bf16x8*)(kn2 + gk1);                                  \
        vpreA = *(const f16x8*)(vn2 + gvt0);                                  \
        vpreB = *(const f16x8*)(vn2 + gvt1);                                  \
      }                                                                       \
    }                                                                         \
    /* softmax (max-free) + f16 pack + permlane */                            \
    unsigned pw[16];                                                          \
    _Pragma("unroll") for (int f = 0; f < 4; ++f) {                           \
      int rb = (f & 1) * 8;                                                   \
      _Pragma("unroll") for (int i = 0; i < 4; ++i) {                         \
        float a = (f >> 1) ? s1[rb + 2 * i] : s0[rb + 2 * i];                 \
        float c = (f >> 1) ? s1[rb + 2 * i + 1] : s0[rb + 2 * i + 1];         \
        f16x2 pp = pkrtz(__builtin_amdgcn_exp2f(a), __builtin_amdgcn_exp2f(c)); \
        union { unsigned u; f16x2 h; } ec; ec.u = EW_CUR[f][i];               \
        f16x2 pr = pp * ec.h;                                                 \
        if (f & 1) lsum1 = dot2acc(pr, lsum1); else lsum0 = dot2acc(pr, lsum0); \
        union { f16x2 h; unsigned u; } pu; pu.h = pr;                         \
        pw[4 * f + i] = pu.u;                                                 \
      }                                                                       \
      plswap(pw[4 * f + 0], pw[4 * f + 2]);                                   \
      plswap(pw[4 * f + 1], pw[4 * f + 3]);                                   \
    }                                                                         \
    /* O^T += V^T * P^T */                                                    \
    __builtin_amdgcn_s_setprio(1);                                            \
    _Pragma("unroll") for (int ks = 0; ks < 4; ++ks) {                        \
      union { unsigned u[4]; f16x8 v; } pf;                                   \
      _Pragma("unroll") for (int i = 0; i < 4; ++i) pf.u[i] = pw[4 * ks + i]; \
      f16x8 vf0 = *(const f16x8*)&Vb[lq * 72 + 16 * ks + 8 * hi];             \
      o0 = MFMA32_F16(vf0, pf.v, o0);                                         \
      f16x8 vf1 = *(const f16x8*)&Vb[(32 + lq) * 72 + 16 * ks + 8 * hi];      \
      o1 = MFMA32_F16(vf1, pf.v, o1);                                         \
    }                                                                         \
    __builtin_amdgcn_s_setprio(0);                                            \
    if (!(LAST)) {                                                            \
      asm volatile("s_waitcnt lgkmcnt(0)" ::: "memory");                      \
      __builtin_amdgcn_s_barrier();                                           \
      asm volatile("" ::: "memory");                                          \
    }                                                                         \
  }

    for (int kt2 = 0; kt2 < (NT - 1) / 2; ++kt2) {
      int kt = 2 * kt2;
      ATTN_BODY(0, kt, EwA, EwB, false);
      ATTN_BODY(1, kt + 1, EwB, EwA, false);
    }
    ATTN_BODY(0, NT - 1, EwA, EwB, true);
#undef ATTN_BODY

    // epilogue: complete row sums, normalize, transpose via LDS [128][72]
    float lsum = lsum0 + lsum1;
    lsum += __shfl_xor(lsum, 32, 64);
    float inv = 1.f / lsum;

    __syncthreads();
    unsigned short* Ot = &LDSU[0][0];        // [128][72] bf16
    const int orow = (w * 32 + lq) * 72;
#pragma unroll
    for (int dt = 0; dt < 2; ++dt) {
#pragma unroll
      for (int j = 0; j < 8; ++j) {
        float v0 = (dt ? o1[2 * j] : o0[2 * j]) * inv;
        float v1 = (dt ? o1[2 * j + 1] : o0[2 * j + 1]) * inv;
        unsigned pk;
        asm("v_cvt_pk_bf16_f32 %0, %1, %2" : "=v"(pk) : "v"(v0), "v"(v1));
        int d = ((2 * j) & 3) + 8 * ((2 * j) >> 2) + 4 * hi + 32 * dt;
        *(unsigned*)&Ot[orow + d] = pk;
      }
    }
    __syncthreads();
#pragma unroll
    for (int i = 0; i < 4; ++i) {
      int c = tid + 256 * i;
      int ql = c >> 3, du = c & 7;
      int tok = qt * 128 + ql;
      if (tok < N_TOK) {
        u32x4 val = *(const u32x4*)&Ot[ql * 72 + du * 8];
        *(u32x4*)&attn_out[((size_t)b * N_TOK + tok) * CDIM + head * DH + du * 8] = val;
      }
    }
  }
}

// ---------------------------------------------------------------------------
// Final projection (f32 out) and fallback-path projection (bf16 split out).
// ---------------------------------------------------------------------------
template<bool IN_F32, int OMODE>
__global__ __launch_bounds__(256)
void proj_gemm(const void* __restrict__ Ain, const float* __restrict__ W,
               const float* __restrict__ bias, void* __restrict__ Out,
               float out_scale)
{
  __shared__ __align__(16) unsigned short xs[64][136];
  __shared__ __align__(16) unsigned short wsh[128][136];
  const int tid = threadIdx.x;
  const int m0 = blockIdx.x * 64;
  const int w = tid >> 6, l = tid & 63;
  const int lk = l & 15, lg = l >> 4;

  stage_w(W, wsh, tid);
  if (IN_F32) {
    const float4* Xv = (const float4*)((const float*)Ain + (size_t)m0 * CDIM);
#pragma unroll
    for (int i = 0; i < 8; ++i) {
      int f = tid + i * 256;
      float4 v = Xv[f];
      int row = f >> 5, col = (f & 31) << 2;
      u16x4 pk = { f2bf(v.x), f2bf(v.y), f2bf(v.z), f2bf(v.w) };
      *(u16x4*)&xs[row][col] = pk;
    }
  } else {
    const bf16x8* Xv = (const bf16x8*)((const unsigned short*)Ain + (size_t)m0 * CDIM);
#pragma unroll
    for (int i = 0; i < 4; ++i) {
      int c = tid + i * 256;
      bf16x8 v = Xv[c];
      int row = c >> 4, col = (c & 15) << 3;
      *(bf16x8*)&xs[row][col] = v;
    }
  }
  __syncthreads();

  f32x4 acc[8];
  mfma_block(xs, wsh, w, lk, lg, acc);

#pragma unroll
  for (int reg = 0; reg < 4; ++reg) {
    int row = m0 + w * 16 + 4 * lg + reg;
    int bb = row / N_TOK;
    int tok = row - bb * N_TOK;
#pragma unroll
    for (int nf = 0; nf < 8; ++nf) {
      int col = nf * 16 + lk;
      float val = (acc[nf][reg] + bias[col]) * out_scale;
      if (OMODE == 0) {
        ((float*)Out)[(size_t)row * CDIM + col] = val;
      } else {
        int head = nf >> 2;
        int d = col & 63;
        size_t idx = ((size_t)(bb * NHEAD + head) * N_TOK + tok) * DH + d;
        ((unsigned short*)Out)[idx] = f2bf(val);
      }
    }
  }
}

// ---------------------------------------------------------------------------
// Fallback attention (R3-proven, bf16 V row-major, direct relpos).
// ---------------------------------------------------------------------------
__global__ __launch_bounds__(256)
void attn_fallback(const unsigned short* __restrict__ q_ws,
                   const unsigned short* __restrict__ k_ws,
                   const unsigned short* __restrict__ v_ws,
                   const float* __restrict__ relpos,
                   unsigned short* __restrict__ attn_out)
{
  __shared__ __align__(16) unsigned short Ks[64][72];
  __shared__ __align__(16) unsigned short Vts[64][72];
  __shared__ __align__(16) unsigned short Ps[4][16][72];

  const int b = blockIdx.x, qt = blockIdx.y, head = blockIdx.z;
  const int tid = threadIdx.x;
  const int w = tid >> 6, l = tid & 63;
  const int lk = l & 15, lg = l >> 4;

  const size_t bh = ((size_t)b * NHEAD + head) * N_TOK;
  const unsigned short* Qp = q_ws + (bh + (size_t)qt * 64) * DH;
  const unsigned short* Kp = k_ws + bh * DH;
  const unsigned short* Vg = v_ws + bh * DH;

  bf16x8 qf0, qf1;
  {
    const unsigned short* qrow = Qp + (size_t)(w * 16 + lk) * DH + 8 * lg;
    qf0 = *(const bf16x8*)qrow;
    qf1 = *(const bf16x8*)(qrow + 32);
  }

  const int kr0 = tid >> 3;
  const int ku = (tid & 7) << 3;
  const int gk0 = kr0 * DH + ku;
  const int gk1 = gk0 + 32 * DH;
  const int vkey = tid & 63;
  const int vd0 = (tid >> 6) << 3;
  const int gv0 = vkey * DH + vd0;
  const int gv1 = gv0 + 32;

  const int qrow0 = qt * 64 + w * 16;
  const float* rpb = relpos + (size_t)head * N_TOK * N_TOK +
                     (size_t)(qrow0 + 4 * lg) * N_TOK + lk;

  float l_run[4] = {0.f, 0.f, 0.f, 0.f};
  f32x4 acc[4];
#pragma unroll
  for (int nf = 0; nf < 4; ++nf) acc[nf] = (f32x4){0.f, 0.f, 0.f, 0.f};

  bf16x8 kpreA = *(const bf16x8*)(Kp + gk0);
  bf16x8 kpreB = *(const bf16x8*)(Kp + gk1);
  bf16x8 vpreA = *(const bf16x8*)(Vg + gv0);
  bf16x8 vpreB = *(const bf16x8*)(Vg + gv1);

  for (int kt = 0; kt < NT; ++kt) {
    float rp[4][4];
#pragma unroll
    for (int r = 0; r < 4; ++r)
#pragma unroll
      for (int ct = 0; ct < 4; ++ct)
        rp[ct][r] = rpb[(size_t)r * N_TOK + kt * 64 + ct * 16];

    asm volatile("s_waitcnt lgkmcnt(0)" ::: "memory");
    __builtin_amdgcn_s_barrier();
    asm volatile("" ::: "memory");

    *(bf16x8*)&Ks[kr0][ku] = kpreA;
    *(bf16x8*)&Ks[kr0 + 32][ku] = kpreB;
#pragma unroll
    for (int j = 0; j < 8; ++j) Vts[vd0 + j][vkey] = ((const unsigned short*)&vpreA)[j];
#pragma unroll
    for (int j = 0; j < 8; ++j) Vts[vd0 + 32 + j][vkey] = ((const unsigned short*)&vpreB)[j];

    if (kt + 1 < NT) {
      const unsigned short* kn = Kp + (size_t)(kt + 1) * 64 * DH;
      const unsigned short* vn = Vg + (size_t)(kt + 1) * 64 * DH;
      kpreA = *(const bf16x8*)(kn + gk0);
      kpreB = *(const bf16x8*)(kn + gk1);
      vpreA = *(const bf16x8*)(vn + gv0);
      vpreB = *(const bf16x8*)(vn + gv1);
    }

    asm volatile("s_waitcnt lgkmcnt(0)" ::: "memory");
    __builtin_amdgcn_s_barrier();
    asm volatile("" ::: "memory");

    f32x4 s[4];
#pragma unroll
    for (int ct = 0; ct < 4; ++ct) s[ct] = (f32x4){0.f, 0.f, 0.f, 0.f};
#pragma unroll
    for (int ct = 0; ct < 4; ++ct) {
      bf16x8 kb0 = *(const bf16x8*)&Ks[ct * 16 + lk][8 * lg];
      s[ct] = MFMA16(qf0, kb0, s[ct]);
      bf16x8 kb1 = *(const bf16x8*)&Ks[ct * 16 + lk][32 + 8 * lg];
      s[ct] = MFMA16(qf1, kb1, s[ct]);
    }

#pragma unroll
    for (int ct = 0; ct < 4; ++ct) {
      float p0 = __builtin_amdgcn_exp2f(fmaf(rp[ct][0], LOG2E, s[ct][0]));
      float p1 = __builtin_amdgcn_exp2f(fmaf(rp[ct][1], LOG2E, s[ct][1]));
      float p2 = __builtin_amdgcn_exp2f(fmaf(rp[ct][2], LOG2E, s[ct][2]));
      float p3 = __builtin_amdgcn_exp2f(fmaf(rp[ct][3], LOG2E, s[ct][3]));
      l_run[0] += p0; l_run[1] += p1; l_run[2] += p2; l_run[3] += p3;
      Ps[w][4 * lg + 0][ct * 16 + lk] = f2bf(p0);
      Ps[w][4 * lg + 1][ct * 16 + lk] = f2bf(p1);
      Ps[w][4 * lg + 2][ct * 16 + lk] = f2bf(p2);
      Ps[w][4 * lg + 3][ct * 16 + lk] = f2bf(p3);
    }

    bf16x8 pa0 = *(const bf16x8*)&Ps[w][lk][8 * lg];
    bf16x8 pa1 = *(const bf16x8*)&Ps[w][lk][32 + 8 * lg];
#pragma unroll
    for (int nf = 0; nf < 4; ++nf) {
      bf16x8 vb0 = *(const bf16x8*)&Vts[nf * 16 + lk][8 * lg];
      acc[nf] = MFMA16(pa0, vb0, acc[nf]);
      bf16x8 vb1 = *(const bf16x8*)&Vts[nf * 16 + lk][32 + 8 * lg];
      acc[nf] = MFMA16(pa1, vb1, acc[nf]);
    }
  }

#pragma unroll
  for (int m = 1; m <= 8; m <<= 1)
#pragma unroll
    for (int r = 0; r < 4; ++r)
      l_run[r] += __shfl_xor(l_run[r], m, 64);

#pragma unroll
  for (int r = 0; r < 4; ++r) {
    int tok = qrow0 + 4 * lg + r;
    float inv = 1.f / l_run[r];
#pragma unroll
    for (int nf = 0; nf < 4; ++nf) {
      attn_out[((size_t)b * N_TOK + tok) * CDIM + head * DH + nf * 16 + lk] =
          f2bf(acc[nf][r] * inv);
    }
  }
}

// ---------------------------------------------------------------------------
extern "C" void kernel_launch(void* const* d_in, const int* in_sizes, int n_in,
                              void* d_out, int out_size, void* d_ws, size_t ws_size,
                              hipStream_t stream) {
  (void)in_sizes; (void)n_in; (void)out_size;
  const float* x      = (const float*)d_in[0];
  const float* relpos = (const float*)d_in[3];
  const float* Wq = (const float*)d_in[4];  const float* bq = (const float*)d_in[5];
  const float* Wk = (const float*)d_in[6];  const float* bk = (const float*)d_in[7];
  const float* Wv = (const float*)d_in[8];  const float* bv = (const float*)d_in[9];
  const float* Wp = (const float*)d_in[10]; const float* bp = (const float*)d_in[11];

  const size_t QKV_ELEMS = (size_t)BATCH * NHEAD * N_TOK * DH;       // 3,211,264
  const size_t E_ELEMS   = (size_t)NHEAD * NT * N_TOK * DH;          // 19,668,992

  unsigned short* q_ws  = (unsigned short*)d_ws;
  unsigned short* k_ws  = q_ws + QKV_ELEMS;
  unsigned short* v_ws  = k_ws + QKV_ELEMS;   // V^T [b][h][d][tok] f16
  unsigned short* ao_ws = v_ws + QKV_ELEMS;   // [B][N][C] bf16
  __half* E_ws = (__half*)(ao_ws + QKV_ELEMS);
  int* counter = (int*)(E_ws + E_ELEMS);

  const size_t need_mid = (4 * QKV_ELEMS + E_ELEMS) * sizeof(unsigned short) + 256;

  dim3 blk(256);

  if (ws_size >= need_mid) {
    hipMemsetAsync(counter, 0, sizeof(int), stream);
    pre_kernel<<<MTILES + EXPBLKS, blk, 0, stream>>>(
        x, Wq, bq, Wk, bk, Wv, bv, q_ws, k_ws, v_ws, relpos, (__half*)E_ws);
    attn32p<<<512, blk, 0, stream>>>(
        q_ws, k_ws, v_ws, (const __half*)E_ws, ao_ws, counter);
  } else {
    proj_gemm<true, 1><<<MTILES, blk, 0, stream>>>((const void*)x, Wq, bq, (void*)q_ws, QK_SCALE);
    proj_gemm<true, 1><<<MTILES, blk, 0, stream>>>((const void*)x, Wk, bk, (void*)k_ws, 1.f);
    proj_gemm<true, 1><<<MTILES, blk, 0, stream>>>((const void*)x, Wv, bv, (void*)v_ws, 1.f);
    attn_fallback<<<dim3(BATCH, N_TOK / 64, NHEAD), blk, 0, stream>>>(
        q_ws, k_ws, v_ws, relpos, ao_ws);
  }

  proj_gemm<false, 0><<<MTILES, blk, 0, stream>>>((const void*)ao_ws, Wp, bp, d_out, 1.f);
}

// Round 17
// 107.508 us; speedup vs baseline: 1.0926x; 1.0926x over previous
//
#include <hip/hip_runtime.h>
#include <hip/hip_fp16.h>

#define N_TOK 3136
#define DH 64
#define NHEAD 2
#define CDIM 128
#define BATCH 8
#define NT 49                      // kv tiles of 64
#define MTILES ((BATCH * N_TOK) / 64) // 392
#define EXPBLKS (NHEAD * NT * (N_TOK / 64)) // 4802
#define QK_SCALE 0.18033688011112f // 0.125 * log2(e)
#define LOG2E 1.4426950408889634f

typedef __attribute__((ext_vector_type(8))) short bf16x8;
typedef __attribute__((ext_vector_type(8))) _Float16 f16x8;
typedef __attribute__((ext_vector_type(2))) _Float16 f16x2;
typedef __attribute__((ext_vector_type(2))) __fp16 fp16x2;
typedef __attribute__((ext_vector_type(4))) float f32x4;
typedef __attribute__((ext_vector_type(16))) float f32x16;
typedef __attribute__((ext_vector_type(4))) unsigned short u16x4;
typedef __attribute__((ext_vector_type(4))) unsigned int u32x4;

__device__ __forceinline__ unsigned short f2bf(float f) {
  unsigned int u = __float_as_uint(f);
  u += 0x7fffu + ((u >> 16) & 1u);
  return (unsigned short)(u >> 16);
}

#define MFMA16(a, b, c)    __builtin_amdgcn_mfma_f32_16x16x32_bf16(a, b, c, 0, 0, 0)
#define MFMA32_BF(a, b, c) __builtin_amdgcn_mfma_f32_32x32x16_bf16(a, b, c, 0, 0, 0)
#define MFMA32_F16(a, b, c) __builtin_amdgcn_mfma_f32_32x32x16_f16(a, b, c, 0, 0, 0)

__device__ __forceinline__ void plswap(unsigned& a, unsigned& b) {
  asm volatile("v_permlane32_swap_b32 %0, %1" : "+v"(a), "+v"(b));
}

__device__ __forceinline__ f16x2 pkrtz(float a, float b) {
  union { fp16x2 p; f16x2 h; } cv;
  cv.p = __builtin_amdgcn_cvt_pkrtz(a, b);
  return cv.h;
}

__device__ __forceinline__ float dot2acc(f16x2 pr, float acc) {
#if __has_builtin(__builtin_amdgcn_fdot2)
  union { f16x2 h; fp16x2 p; } c; c.h = pr;
  fp16x2 ones = {(__fp16)1.0f, (__fp16)1.0f};
  return __builtin_amdgcn_fdot2(c.p, ones, acc, false);
#else
  return acc + (float)pr[0] + (float)pr[1];
#endif
}

// ---------------------------------------------------------------------------
// Shared GEMM helpers (64-row x-tile  x  128x128 W, MFMA 16x16x32)
// ---------------------------------------------------------------------------
__device__ __forceinline__ void stage_w(const float* __restrict__ W,
                                        unsigned short (*wsh)[136], int tid) {
  const float4* Wv4 = (const float4*)W;
#pragma unroll
  for (int i = 0; i < 16; ++i) {
    int f = tid + i * 256;
    float4 v = Wv4[f];
    int row = f >> 5, col = (f & 31) << 2;
    u16x4 pk = { f2bf(v.x), f2bf(v.y), f2bf(v.z), f2bf(v.w) };
    *(u16x4*)&wsh[row][col] = pk;
  }
}

__device__ __forceinline__ void mfma_block(const unsigned short (*xs)[136],
                                           const unsigned short (*wsh)[136],
                                           int w, int lk, int lg, f32x4* acc) {
#pragma unroll
  for (int nf = 0; nf < 8; ++nf) acc[nf] = (f32x4){0.f, 0.f, 0.f, 0.f};
#pragma unroll
  for (int kk = 0; kk < 4; ++kk) {
    bf16x8 a = *(const bf16x8*)&xs[w * 16 + lk][kk * 32 + 8 * lg];
#pragma unroll
    for (int nf = 0; nf < 8; ++nf) {
      bf16x8 b = *(const bf16x8*)&wsh[nf * 16 + lk][kk * 32 + 8 * lg];
      acc[nf] = MFMA16(a, b, acc[nf]);
    }
  }
}

// ---------------------------------------------------------------------------
// pre_kernel: fused {QKV projection | exp(relpos)} — one grid so the BW-bound
// exp blocks overlap the MFMA-bound projection blocks.
// Q,K -> bf16 [b][h][tok][64] (Q pre-scaled); V -> f16 TRANSPOSED [b][h][d][tok].
// E[h][kt][q][didx] f16 = exp(relpos), didx = attn-fragment-ordered key.
// ---------------------------------------------------------------------------
__global__ __launch_bounds__(256)
void pre_kernel(const float* __restrict__ x,
                const float* __restrict__ Wq, const float* __restrict__ bq,
                const float* __restrict__ Wk, const float* __restrict__ bk,
                const float* __restrict__ Wv, const float* __restrict__ bv,
                unsigned short* __restrict__ qo, unsigned short* __restrict__ ko,
                unsigned short* __restrict__ vo,
                const float* __restrict__ rp, __half* __restrict__ E)
{
  __shared__ __align__(16) unsigned short xs[64][136];
  __shared__ __align__(16) unsigned short wsh[128][136];
  const int tid = threadIdx.x;

  if (blockIdx.x >= MTILES) {
    const int eb = blockIdx.x - MTILES;
    const int hkt = eb % (NHEAD * NT);
    const int q0 = (eb / (NHEAD * NT)) * 64;
    const int h = hkt / NT, kt = hkt % NT;
    const int kp = tid & 63;
    const int qi = tid >> 6;

    const int ct = kp >> 5;
    const int kpp = kp & 31;
    const int hi = (kpp >> 2) & 1;
    const int r = (kpp & 3) + ((kpp >> 3) << 2);
    const int didx = hi * 32 + ct * 16 + r;

    const float* src = rp + ((size_t)h * N_TOK + q0) * N_TOK + kt * 64 + kp;
    __half* dst = E + (((size_t)h * NT + kt) * N_TOK + q0) * 64 + didx;
#pragma unroll
    for (int i = 0; i < 16; ++i) {
      int q = qi * 16 + i;
      float v = __expf(src[(size_t)q * N_TOK]);
      dst[(size_t)q * 64] = __float2half(v);
    }
    return;
  }

  const int m0 = blockIdx.x * 64;
  const int w = tid >> 6, l = tid & 63;
  const int lk = l & 15, lg = l >> 4;

  {
    const float4* Xv = (const float4*)(x + (size_t)m0 * CDIM);
#pragma unroll
    for (int i = 0; i < 8; ++i) {
      int f = tid + i * 256;
      float4 v = Xv[f];
      int row = f >> 5, col = (f & 31) << 2;
      u16x4 pk = { f2bf(v.x), f2bf(v.y), f2bf(v.z), f2bf(v.w) };
      *(u16x4*)&xs[row][col] = pk;
    }
  }
  stage_w(Wq, wsh, tid);
  __syncthreads();

  f32x4 acc[8];

  // Q
  mfma_block(xs, wsh, w, lk, lg, acc);
#pragma unroll
  for (int reg = 0; reg < 4; ++reg) {
    int row = m0 + w * 16 + 4 * lg + reg;
    int bb = row / N_TOK, tok = row - bb * N_TOK;
#pragma unroll
    for (int nf = 0; nf < 8; ++nf) {
      int col = nf * 16 + lk;
      float val = (acc[nf][reg] + bq[col]) * QK_SCALE;
      qo[((size_t)(bb * NHEAD + (nf >> 2)) * N_TOK + tok) * DH + (col & 63)] = f2bf(val);
    }
  }
  __syncthreads();

  // K
  stage_w(Wk, wsh, tid);
  __syncthreads();
  mfma_block(xs, wsh, w, lk, lg, acc);
#pragma unroll
  for (int reg = 0; reg < 4; ++reg) {
    int row = m0 + w * 16 + 4 * lg + reg;
    int bb = row / N_TOK, tok = row - bb * N_TOK;
#pragma unroll
    for (int nf = 0; nf < 8; ++nf) {
      int col = nf * 16 + lk;
      float val = acc[nf][reg] + bk[col];
      ko[((size_t)(bb * NHEAD + (nf >> 2)) * N_TOK + tok) * DH + (col & 63)] = f2bf(val);
    }
  }
  __syncthreads();

  // V (transposed f16: [b][h][d][tok])
  stage_w(Wv, wsh, tid);
  __syncthreads();
  mfma_block(xs, wsh, w, lk, lg, acc);
#pragma unroll
  for (int reg = 0; reg < 4; ++reg) {
    int row = m0 + w * 16 + 4 * lg + reg;
    int bb = row / N_TOK, tok = row - bb * N_TOK;
#pragma unroll
    for (int nf = 0; nf < 8; ++nf) {
      int col = nf * 16 + lk;
      float val = acc[nf][reg] + bv[col];
      size_t idx = ((size_t)(bb * NHEAD + (nf >> 2)) * DH + (col & 63)) * N_TOK + tok;
      vo[idx] = __half_as_ushort(__float2half(val));
    }
  }
}

// ---------------------------------------------------------------------------
// attn32: swapped-operand 32x32 flash attention, zero-LDS P path, dbuf LDS
// (one barrier per tile), E prefetched one tile ahead, V pre-transposed in
// global so staging is pure b128 (same as K).
// WG = 4 waves x 32 q = 128 q. Grid (B, 25, NHEAD) = 400 blocks.
// (R15-proven: measured 79.2 us, total 107.6 us, passed post-timing.)
// ---------------------------------------------------------------------------
__global__ __launch_bounds__(256)
void attn32(const unsigned short* __restrict__ q_ws,
            const unsigned short* __restrict__ k_ws,
            const unsigned short* __restrict__ v_ws,   // V^T [b][h][d][tok] f16
            const __half* __restrict__ E,
            unsigned short* __restrict__ attn_out)
{
  __shared__ __align__(16) unsigned short LDSU[2][9216]; // [buf][K 4608 | V 4608]

  const int b = blockIdx.x, qt = blockIdx.y, head = blockIdx.z;
  const int tid = threadIdx.x;
  const int w = tid >> 6, l = tid & 63;
  const int lq = l & 31, hi = l >> 5;

  const size_t bh = ((size_t)b * NHEAD + head) * N_TOK;
  const unsigned short* Kp = k_ws + bh * DH;
  const _Float16* Vt = (const _Float16*)v_ws + bh * DH;  // V^T base

  int qg = qt * 128 + w * 32 + lq;
  if (qg > N_TOK - 1) qg = N_TOK - 1;

  // Q B-frags: qf[ks] holds Q[qg][16*ks + 8*hi + 0..7]
  bf16x8 qf[4];
  {
    const unsigned short* qrow = q_ws + (bh + (size_t)qg) * DH + 8 * hi;
#pragma unroll
    for (int ks = 0; ks < 4; ++ks) qf[ks] = *(const bf16x8*)(qrow + 16 * ks);
  }

  // staging mapping (identical for K and V^T): row = tid>>3 (+32), unit = tid&7
  const int kr0 = tid >> 3, ku = tid & 7;
  const int kofs = kr0 * 72 + ku * 8;
  const int gk0 = kr0 * DH + ku * 8, gk1 = gk0 + 32 * DH;
  const int gvt0 = kr0 * N_TOK + ku * 8, gvt1 = gvt0 + 32 * N_TOK;

  const __half* Eb = E + (((size_t)head * NT) * N_TOK + (size_t)qg) * DH + hi * 32;

  float lsum0 = 0.f, lsum1 = 0.f;
  f32x16 o0, o1;
#pragma unroll
  for (int i = 0; i < 16; ++i) { o0[i] = 0.f; o1[i] = 0.f; }

  // ---- prologue: tile 0 ----
  bf16x8 kpreA = *(const bf16x8*)(Kp + gk0);
  bf16x8 kpreB = *(const bf16x8*)(Kp + gk1);
  f16x8 vpreA = *(const f16x8*)(Vt + gvt0);
  f16x8 vpreB = *(const f16x8*)(Vt + gvt1);

  u32x4 EwA[4], EwB[4];
  {
    const u32x4* ep = (const u32x4*)Eb;   // kt = 0
#pragma unroll
    for (int f = 0; f < 4; ++f) EwA[f] = ep[f];
  }

  *(bf16x8*)&LDSU[0][kofs] = kpreA;
  *(bf16x8*)&LDSU[0][kofs + 32 * 72] = kpreB;
  *(f16x8*)&LDSU[0][4608 + kofs] = vpreA;
  *(f16x8*)&LDSU[0][4608 + kofs + 32 * 72] = vpreB;
  {
    const unsigned short* kn = Kp + (size_t)64 * DH;
    const _Float16* vn = Vt + 64;
    kpreA = *(const bf16x8*)(kn + gk0);
    kpreB = *(const bf16x8*)(kn + gk1);
    vpreA = *(const f16x8*)(vn + gvt0);
    vpreB = *(const f16x8*)(vn + gvt1);
  }
  asm volatile("s_waitcnt lgkmcnt(0)" ::: "memory");
  __builtin_amdgcn_s_barrier();
  asm volatile("" ::: "memory");

#define ATTN_BODY(PH, KT, EW_CUR, EW_NXT, LAST)                               \
  {                                                                           \
    const unsigned short* Kb = &LDSU[PH][0];                                  \
    const unsigned short* Vb = &LDSU[PH][4608];                               \
    unsigned short* Kn = &LDSU[PH ^ 1][0];                                    \
    unsigned short* Vn = &LDSU[PH ^ 1][4608];                                 \
    if (!(LAST)) { /* issue E(kt+1) */                                        \
      const u32x4* ep = (const u32x4*)(Eb + (size_t)((KT) + 1) * (N_TOK * DH)); \
      _Pragma("unroll") for (int f = 0; f < 4; ++f) EW_NXT[f] = ep[f];        \
    }                                                                         \
    /* S^T = K * Q^T */                                                       \
    f32x16 s0, s1;                                                            \
    _Pragma("unroll") for (int i = 0; i < 16; ++i) { s0[i] = 0.f; s1[i] = 0.f; } \
    __builtin_amdgcn_s_setprio(1);                                            \
    _Pragma("unroll") for (int ks = 0; ks < 4; ++ks) {                        \
      bf16x8 kf0 = *(const bf16x8*)&Kb[lq * 72 + 16 * ks + 8 * hi];           \
      s0 = MFMA32_BF(kf0, qf[ks], s0);                                        \
      bf16x8 kf1 = *(const bf16x8*)&Kb[(32 + lq) * 72 + 16 * ks + 8 * hi];    \
      s1 = MFMA32_BF(kf1, qf[ks], s1);                                        \
    }                                                                         \
    __builtin_amdgcn_s_setprio(0);                                            \
    if (!(LAST)) { /* store tile kt+1 into other buf; issue kt+2 */           \
      *(bf16x8*)&Kn[kofs] = kpreA;                                            \
      *(bf16x8*)&Kn[kofs + 32 * 72] = kpreB;                                  \
      *(f16x8*)&Vn[kofs] = vpreA;                                             \
      *(f16x8*)&Vn[kofs + 32 * 72] = vpreB;                                   \
      if ((KT) + 2 < NT) {                                                    \
        const unsigned short* kn2 = Kp + (size_t)((KT) + 2) * 64 * DH;        \
        const _Float16* vn2 = Vt + (size_t)((KT) + 2) * 64;                   \
        kpreA = *(const bf16x8*)(kn2 + gk0);                                  \
        kpreB = *(const bf16x8*)(kn2 + gk1);                                  \
        vpreA = *(const f16x8*)(vn2 + gvt0);                                  \
        vpreB = *(const f16x8*)(vn2 + gvt1);                                  \
      }                                                                       \
    }                                                                         \
    /* softmax (max-free) + f16 pack + permlane */                            \
    unsigned pw[16];                                                          \
    _Pragma("unroll") for (int f = 0; f < 4; ++f) {                           \
      int rb = (f & 1) * 8;                                                   \
      _Pragma("unroll") for (int i = 0; i < 4; ++i) {                         \
        float a = (f >> 1) ? s1[rb + 2 * i] : s0[rb + 2 * i];                 \
        float c = (f >> 1) ? s1[rb + 2 * i + 1] : s0[rb + 2 * i + 1];         \
        f16x2 pp = pkrtz(__builtin_amdgcn_exp2f(a), __builtin_amdgcn_exp2f(c)); \
        union { unsigned u; f16x2 h; } ec; ec.u = EW_CUR[f][i];               \
        f16x2 pr = pp * ec.h;                                                 \
        if (f & 1) lsum1 = dot2acc(pr, lsum1); else lsum0 = dot2acc(pr, lsum0); \
        union { f16x2 h; unsigned u; } pu; pu.h = pr;                         \
        pw[4 * f + i] = pu.u;                                                 \
      }                                                                       \
      plswap(pw[4 * f + 0], pw[4 * f + 2]);                                   \
      plswap(pw[4 * f + 1], pw[4 * f + 3]);                                   \
    }                                                                         \
    /* O^T += V^T * P^T */                                                    \
    __builtin_amdgcn_s_setprio(1);                                            \
    _Pragma("unroll") for (int ks = 0; ks < 4; ++ks) {                        \
      union { unsigned u[4]; f16x8 v; } pf;                                   \
      _Pragma("unroll") for (int i = 0; i < 4; ++i) pf.u[i] = pw[4 * ks + i]; \
      f16x8 vf0 = *(const f16x8*)&Vb[lq * 72 + 16 * ks + 8 * hi];             \
      o0 = MFMA32_F16(vf0, pf.v, o0);                                         \
      f16x8 vf1 = *(const f16x8*)&Vb[(32 + lq) * 72 + 16 * ks + 8 * hi];      \
      o1 = MFMA32_F16(vf1, pf.v, o1);                                         \
    }                                                                         \
    __builtin_amdgcn_s_setprio(0);                                            \
    if (!(LAST)) {                                                            \
      asm volatile("s_waitcnt lgkmcnt(0)" ::: "memory");                      \
      __builtin_amdgcn_s_barrier();                                           \
      asm volatile("" ::: "memory");                                          \
    }                                                                         \
  }

  for (int kt2 = 0; kt2 < (NT - 1) / 2; ++kt2) {
    int kt = 2 * kt2;
    ATTN_BODY(0, kt, EwA, EwB, false);
    ATTN_BODY(1, kt + 1, EwB, EwA, false);
  }
  ATTN_BODY(0, NT - 1, EwA, EwB, true);
#undef ATTN_BODY

  // epilogue: complete row sums (other hi half), normalize, transpose via LDS
  float lsum = lsum0 + lsum1;
  lsum += __shfl_xor(lsum, 32, 64);
  float inv = 1.f / lsum;

  __syncthreads();
  unsigned short* Ot = &LDSU[0][0];        // [128][72] bf16
  const int orow = (w * 32 + lq) * 72;
#pragma unroll
  for (int dt = 0; dt < 2; ++dt) {
#pragma unroll
    for (int j = 0; j < 8; ++j) {
      float v0 = (dt ? o1[2 * j] : o0[2 * j]) * inv;
      float v1 = (dt ? o1[2 * j + 1] : o0[2 * j + 1]) * inv;
      unsigned pk;
      asm("v_cvt_pk_bf16_f32 %0, %1, %2" : "=v"(pk) : "v"(v0), "v"(v1));
      int d = ((2 * j) & 3) + 8 * ((2 * j) >> 2) + 4 * hi + 32 * dt;
      *(unsigned*)&Ot[orow + d] = pk;
    }
  }
  __syncthreads();
#pragma unroll
  for (int i = 0; i < 4; ++i) {
    int c = tid + 256 * i;
    int ql = c >> 3, du = c & 7;
    int tok = qt * 128 + ql;
    if (tok < N_TOK) {
      u32x4 val = *(const u32x4*)&Ot[ql * 72 + du * 8];
      *(u32x4*)&attn_out[((size_t)b * N_TOK + tok) * CDIM + head * DH + du * 8] = val;
    }
  }
}

// ---------------------------------------------------------------------------
// Final projection (f32 out) and fallback-path projection (bf16 split out).
// ---------------------------------------------------------------------------
template<bool IN_F32, int OMODE>
__global__ __launch_bounds__(256)
void proj_gemm(const void* __restrict__ Ain, const float* __restrict__ W,
               const float* __restrict__ bias, void* __restrict__ Out,
               float out_scale)
{
  __shared__ __align__(16) unsigned short xs[64][136];
  __shared__ __align__(16) unsigned short wsh[128][136];
  const int tid = threadIdx.x;
  const int m0 = blockIdx.x * 64;
  const int w = tid >> 6, l = tid & 63;
  const int lk = l & 15, lg = l >> 4;

  stage_w(W, wsh, tid);
  if (IN_F32) {
    const float4* Xv = (const float4*)((const float*)Ain + (size_t)m0 * CDIM);
#pragma unroll
    for (int i = 0; i < 8; ++i) {
      int f = tid + i * 256;
      float4 v = Xv[f];
      int row = f >> 5, col = (f & 31) << 2;
      u16x4 pk = { f2bf(v.x), f2bf(v.y), f2bf(v.z), f2bf(v.w) };
      *(u16x4*)&xs[row][col] = pk;
    }
  } else {
    const bf16x8* Xv = (const bf16x8*)((const unsigned short*)Ain + (size_t)m0 * CDIM);
#pragma unroll
    for (int i = 0; i < 4; ++i) {
      int c = tid + i * 256;
      bf16x8 v = Xv[c];
      int row = c >> 4, col = (c & 15) << 3;
      *(bf16x8*)&xs[row][col] = v;
    }
  }
  __syncthreads();

  f32x4 acc[8];
  mfma_block(xs, wsh, w, lk, lg, acc);

#pragma unroll
  for (int reg = 0; reg < 4; ++reg) {
    int row = m0 + w * 16 + 4 * lg + reg;
    int bb = row / N_TOK;
    int tok = row - bb * N_TOK;
#pragma unroll
    for (int nf = 0; nf < 8; ++nf) {
      int col = nf * 16 + lk;
      float val = (acc[nf][reg] + bias[col]) * out_scale;
      if (OMODE == 0) {
        ((float*)Out)[(size_t)row * CDIM + col] = val;
      } else {
        int head = nf >> 2;
        int d = col & 63;
        size_t idx = ((size_t)(bb * NHEAD + head) * N_TOK + tok) * DH + d;
        ((unsigned short*)Out)[idx] = f2bf(val);
      }
    }
  }
}

// ---------------------------------------------------------------------------
// Fallback attention (R3-proven, bf16 V row-major, direct relpos).
// ---------------------------------------------------------------------------
__global__ __launch_bounds__(256)
void attn_fallback(const unsigned short* __restrict__ q_ws,
                   const unsigned short* __restrict__ k_ws,
                   const unsigned short* __restrict__ v_ws,
                   const float* __restrict__ relpos,
                   unsigned short* __restrict__ attn_out)
{
  __shared__ __align__(16) unsigned short Ks[64][72];
  __shared__ __align__(16) unsigned short Vts[64][72];
  __shared__ __align__(16) unsigned short Ps[4][16][72];

  const int b = blockIdx.x, qt = blockIdx.y, head = blockIdx.z;
  const int tid = threadIdx.x;
  const int w = tid >> 6, l = tid & 63;
  const int lk = l & 15, lg = l >> 4;

  const size_t bh = ((size_t)b * NHEAD + head) * N_TOK;
  const unsigned short* Qp = q_ws + (bh + (size_t)qt * 64) * DH;
  const unsigned short* Kp = k_ws + bh * DH;
  const unsigned short* Vg = v_ws + bh * DH;

  bf16x8 qf0, qf1;
  {
    const unsigned short* qrow = Qp + (size_t)(w * 16 + lk) * DH + 8 * lg;
    qf0 = *(const bf16x8*)qrow;
    qf1 = *(const bf16x8*)(qrow + 32);
  }

  const int kr0 = tid >> 3;
  const int ku = (tid & 7) << 3;
  const int gk0 = kr0 * DH + ku;
  const int gk1 = gk0 + 32 * DH;
  const int vkey = tid & 63;
  const int vd0 = (tid >> 6) << 3;
  const int gv0 = vkey * DH + vd0;
  const int gv1 = gv0 + 32;

  const int qrow0 = qt * 64 + w * 16;
  const float* rpb = relpos + (size_t)head * N_TOK * N_TOK +
                     (size_t)(qrow0 + 4 * lg) * N_TOK + lk;

  float l_run[4] = {0.f, 0.f, 0.f, 0.f};
  f32x4 acc[4];
#pragma unroll
  for (int nf = 0; nf < 4; ++nf) acc[nf] = (f32x4){0.f, 0.f, 0.f, 0.f};

  bf16x8 kpreA = *(const bf16x8*)(Kp + gk0);
  bf16x8 kpreB = *(const bf16x8*)(Kp + gk1);
  bf16x8 vpreA = *(const bf16x8*)(Vg + gv0);
  bf16x8 vpreB = *(const bf16x8*)(Vg + gv1);

  for (int kt = 0; kt < NT; ++kt) {
    float rp[4][4];
#pragma unroll
    for (int r = 0; r < 4; ++r)
#pragma unroll
      for (int ct = 0; ct < 4; ++ct)
        rp[ct][r] = rpb[(size_t)r * N_TOK + kt * 64 + ct * 16];

    asm volatile("s_waitcnt lgkmcnt(0)" ::: "memory");
    __builtin_amdgcn_s_barrier();
    asm volatile("" ::: "memory");

    *(bf16x8*)&Ks[kr0][ku] = kpreA;
    *(bf16x8*)&Ks[kr0 + 32][ku] = kpreB;
#pragma unroll
    for (int j = 0; j < 8; ++j) Vts[vd0 + j][vkey] = ((const unsigned short*)&vpreA)[j];
#pragma unroll
    for (int j = 0; j < 8; ++j) Vts[vd0 + 32 + j][vkey] = ((const unsigned short*)&vpreB)[j];

    if (kt + 1 < NT) {
      const unsigned short* kn = Kp + (size_t)(kt + 1) * 64 * DH;
      const unsigned short* vn = Vg + (size_t)(kt + 1) * 64 * DH;
      kpreA = *(const bf16x8*)(kn + gk0);
      kpreB = *(const bf16x8*)(kn + gk1);
      vpreA = *(const bf16x8*)(vn + gv0);
      vpreB = *(const bf16x8*)(vn + gv1);
    }

    asm volatile("s_waitcnt lgkmcnt(0)" ::: "memory");
    __builtin_amdgcn_s_barrier();
    asm volatile("" ::: "memory");

    f32x4 s[4];
#pragma unroll
    for (int ct = 0; ct < 4; ++ct) s[ct] = (f32x4){0.f, 0.f, 0.f, 0.f};
#pragma unroll
    for (int ct = 0; ct < 4; ++ct) {
      bf16x8 kb0 = *(const bf16x8*)&Ks[ct * 16 + lk][8 * lg];
      s[ct] = MFMA16(qf0, kb0, s[ct]);
      bf16x8 kb1 = *(const bf16x8*)&Ks[ct * 16 + lk][32 + 8 * lg];
      s[ct] = MFMA16(qf1, kb1, s[ct]);
    }

#pragma unroll
    for (int ct = 0; ct < 4; ++ct) {
      float p0 = __builtin_amdgcn_exp2f(fmaf(rp[ct][0], LOG2E, s[ct][0]));
      float p1 = __builtin_amdgcn_exp2f(fmaf(rp[ct][1], LOG2E, s[ct][1]));
      float p2 = __builtin_amdgcn_exp2f(fmaf(rp[ct][2], LOG2E, s[ct][2]));
      float p3 = __builtin_amdgcn_exp2f(fmaf(rp[ct][3], LOG2E, s[ct][3]));
      l_run[0] += p0; l_run[1] += p1; l_run[2] += p2; l_run[3] += p3;
      Ps[w][4 * lg + 0][ct * 16 + lk] = f2bf(p0);
      Ps[w][4 * lg + 1][ct * 16 + lk] = f2bf(p1);
      Ps[w][4 * lg + 2][ct * 16 + lk] = f2bf(p2);
      Ps[w][4 * lg + 3][ct * 16 + lk] = f2bf(p3);
    }

    bf16x8 pa0 = *(const bf16x8*)&Ps[w][lk][8 * lg];
    bf16x8 pa1 = *(const bf16x8*)&Ps[w][lk][32 + 8 * lg];
#pragma unroll
    for (int nf = 0; nf < 4; ++nf) {
      bf16x8 vb0 = *(const bf16x8*)&Vts[nf * 16 + lk][8 * lg];
      acc[nf] = MFMA16(pa0, vb0, acc[nf]);
      bf16x8 vb1 = *(const bf16x8*)&Vts[nf * 16 + lk][32 + 8 * lg];
      acc[nf] = MFMA16(pa1, vb1, acc[nf]);
    }
  }

#pragma unroll
  for (int m = 1; m <= 8; m <<= 1)
#pragma unroll
    for (int r = 0; r < 4; ++r)
      l_run[r] += __shfl_xor(l_run[r], m, 64);

#pragma unroll
  for (int r = 0; r < 4; ++r) {
    int tok = qrow0 + 4 * lg + r;
    float inv = 1.f / l_run[r];
#pragma unroll
    for (int nf = 0; nf < 4; ++nf) {
      attn_out[((size_t)b * N_TOK + tok) * CDIM + head * DH + nf * 16 + lk] =
          f2bf(acc[nf][r] * inv);
    }
  }
}

// ---------------------------------------------------------------------------
extern "C" void kernel_launch(void* const* d_in, const int* in_sizes, int n_in,
                              void* d_out, int out_size, void* d_ws, size_t ws_size,
                              hipStream_t stream) {
  (void)in_sizes; (void)n_in; (void)out_size;
  const float* x      = (const float*)d_in[0];
  const float* relpos = (const float*)d_in[3];
  const float* Wq = (const float*)d_in[4];  const float* bq = (const float*)d_in[5];
  const float* Wk = (const float*)d_in[6];  const float* bk = (const float*)d_in[7];
  const float* Wv = (const float*)d_in[8];  const float* bv = (const float*)d_in[9];
  const float* Wp = (const float*)d_in[10]; const float* bp = (const float*)d_in[11];

  const size_t QKV_ELEMS = (size_t)BATCH * NHEAD * N_TOK * DH;       // 3,211,264
  const size_t E_ELEMS   = (size_t)NHEAD * NT * N_TOK * DH;          // 19,668,992

  unsigned short* q_ws  = (unsigned short*)d_ws;
  unsigned short* k_ws  = q_ws + QKV_ELEMS;
  unsigned short* v_ws  = k_ws + QKV_ELEMS;   // V^T [b][h][d][tok] f16
  unsigned short* ao_ws = v_ws + QKV_ELEMS;   // [B][N][C] bf16
  __half* E_ws = (__half*)(ao_ws + QKV_ELEMS);

  const size_t need_mid = (4 * QKV_ELEMS + E_ELEMS) * sizeof(unsigned short);

  dim3 blk(256);

  if (ws_size >= need_mid) {
    pre_kernel<<<MTILES + EXPBLKS, blk, 0, stream>>>(
        x, Wq, bq, Wk, bk, Wv, bv, q_ws, k_ws, v_ws, relpos, (__half*)E_ws);
    attn32<<<dim3(BATCH, (N_TOK + 127) / 128, NHEAD), blk, 0, stream>>>(
        q_ws, k_ws, v_ws, (const __half*)E_ws, ao_ws);
  } else {
    proj_gemm<true, 1><<<MTILES, blk, 0, stream>>>((const void*)x, Wq, bq, (void*)q_ws, QK_SCALE);
    proj_gemm<true, 1><<<MTILES, blk, 0, stream>>>((const void*)x, Wk, bk, (void*)k_ws, 1.f);
    proj_gemm<true, 1><<<MTILES, blk, 0, stream>>>((const void*)x, Wv, bv, (void*)v_ws, 1.f);
    attn_fallback<<<dim3(BATCH, N_TOK / 64, NHEAD), blk, 0, stream>>>(
        q_ws, k_ws, v_ws, relpos, ao_ws);
  }

  proj_gemm<false, 0><<<MTILES, blk, 0, stream>>>((const void*)ao_ws, Wp, bp, d_out, 1.f);
}